// Round 8
// baseline (242.293 us; speedup 1.0000x reference)
//
#include <hip/hip_runtime.h>

typedef unsigned short u16;
typedef __attribute__((ext_vector_type(8))) short short8;   // 8 bf16 = 4 VGPRs
typedef __attribute__((ext_vector_type(4))) float floatx4;

#define MFMA16(a, b, c) __builtin_amdgcn_mfma_f32_16x16x32_bf16(a, b, c, 0, 0, 0)

__device__ inline u16 bf16rn(float x) {
    unsigned u = __float_as_uint(x);
    u += 0x7fffu + ((u >> 16) & 1u);
    return (u16)(u >> 16);
}
__device__ inline float bf16tof(u16 h) { return __uint_as_float(((unsigned)h) << 16); }
__device__ inline short8 ld8(const u16* p) { return *(const short8*)p; }
__device__ inline float exp2fast(float x) { return __builtin_amdgcn_exp2f(x); }

// Q scale: 0.25 * log2(e) — S lands in log2 domain, exp(S)=exp2(S')
#define QSC 0.36067376022224085f

// ---------------------------------------------------------------------------
// Fused prep (one dispatch, 3 block ranges):
//  [0,2048):    conv14 (oc-split x2) -> cph/cpl bf16 hi/lo, 224-padded rows
//  [2048,2560): q-conv 7x7 (2 bg per block) + Q hi/lo conversion (x QSC)
//  [2560,2624): e<32: E transpose+hi/lo (tiled);  e>=32: rel K rows
__global__ __launch_bounds__(256) void k_prep(const float* __restrict__ pose14,
                                              const float* __restrict__ pose7,
                                              const float* __restrict__ E,
                                              const float* __restrict__ rel,
                                              const float* __restrict__ cw,
                                              const float* __restrict__ nw,
                                              u16* __restrict__ cph,
                                              u16* __restrict__ cpl,
                                              u16* __restrict__ Qp,
                                              u16* __restrict__ EhT,
                                              u16* __restrict__ ElT,
                                              u16* __restrict__ Kh,
                                              u16* __restrict__ Kl,
                                              u16* __restrict__ KhT,
                                              u16* __restrict__ KlT) {
    __shared__ __align__(16) float smem[6400];    // 25.6 KB union
    int blk = blockIdx.x, tid = threadIdx.x;

    if (blk < 2048) {                        // ---- conv14 ----
        int oh = blk & 1, bg = blk >> 1;
        float* patch = smem;                 // 16 ic x 256 (16x16 halo)
#pragma unroll
        for (int k = 0; k < 16; ++k) patch[k * 256 + tid] = 0.f;
        __syncthreads();
        const float* pin = pose14 + (size_t)bg * 3136;
        for (int t = tid; t < 3136; t += 256) {
            int p = t >> 4, ic = t & 15;
            int y = p / 14, x = p % 14;
            patch[ic * 256 + (y + 1) * 16 + (x + 1)] = pin[t];
        }
        __syncthreads();
        int g = bg & 31;
        const float* wg = cw + (size_t)g * 2304 + (size_t)oh * 8 * 144;
        if (tid < 196) {
            int y = tid / 14, x = tid % 14;
            int base = (y + 1) * 16 + (x + 1);
            float acc[8];
#pragma unroll
            for (int oc = 0; oc < 8; ++oc) acc[oc] = 0.f;
            for (int ic = 0; ic < 16; ++ic) {
                const float* pr = patch + ic * 256 + base;
                float win[9];
#pragma unroll
                for (int ky = 0; ky < 3; ++ky)
#pragma unroll
                    for (int kx = 0; kx < 3; ++kx)
                        win[ky * 3 + kx] = pr[(ky - 1) * 16 + (kx - 1)];
#pragma unroll
                for (int oc = 0; oc < 8; ++oc)
#pragma unroll
                    for (int kk = 0; kk < 9; ++kk)
                        acc[oc] += win[kk] * wg[oc * 144 + ic * 9 + kk];
            }
#pragma unroll
            for (int oc = 0; oc < 8; ++oc) {
                size_t row = (size_t)bg * 16 + oh * 8 + oc;
                u16 h = bf16rn(acc[oc]);
                cph[row * 224 + tid] = h;
                cpl[row * 224 + tid] = bf16rn(acc[oc] - bf16tof(h));
            }
        }
    } else if (blk < 2560) {                 // ---- q-conv + Q cvt (2 bg) ----
        int idx = blk - 2048, half = tid >> 7, t128 = tid & 127;
        int bg = idx * 2 + half;
        float* patch = smem + half * 2304;         // 16 ic x 144
        float* cvq   = smem + 4608 + half * 832;   // [16][52]
        for (int t = t128; t < 2304; t += 128) patch[t] = 0.f;
        __syncthreads();
        const float* pin = pose7 + (size_t)bg * 784;
        for (int t = t128; t < 784; t += 128) {
            int p = t >> 4, ic = t & 15;
            int y = p / 7, x = p % 7;
            patch[ic * 144 + (y + 1) * 16 + (x + 1)] = pin[t];
        }
        __syncthreads();
        int g = bg & 31;
        int oh = t128 >> 6, lt = t128 & 63;
        const float* wg = nw + (size_t)g * 2304 + (size_t)oh * 8 * 144;
        if (lt < 49) {
            int y = lt / 7, x = lt % 7;
            int base = (y + 1) * 16 + (x + 1);
            float acc[8];
#pragma unroll
            for (int oc = 0; oc < 8; ++oc) acc[oc] = 0.f;
            for (int ic = 0; ic < 16; ++ic) {
                const float* pr = patch + ic * 144 + base;
                float win[9];
#pragma unroll
                for (int ky = 0; ky < 3; ++ky)
#pragma unroll
                    for (int kx = 0; kx < 3; ++kx)
                        win[ky * 3 + kx] = pr[(ky - 1) * 16 + (kx - 1)];
#pragma unroll
                for (int oc = 0; oc < 8; ++oc)
#pragma unroll
                    for (int kk = 0; kk < 9; ++kk)
                        acc[oc] += win[kk] * wg[oc * 144 + ic * 9 + kk];
            }
#pragma unroll
            for (int oc = 0; oc < 8; ++oc) {
                int f = (oh * 8 + oc) * 49 + lt;
                cvq[(f & 15) * 52 + (f >> 4)] = acc[oc];
            }
        }
        __syncthreads();
        if (t128 < 49) {
            float v[16];
#pragma unroll
            for (int k = 0; k < 16; ++k) v[k] = cvq[k * 52 + t128];
            unsigned hw[8], lw[8];
#pragma unroll
            for (int t = 0; t < 8; ++t) {
                float x0 = v[2*t] * QSC, x1 = v[2*t+1] * QSC;
                u16 h0 = bf16rn(x0), h1 = bf16rn(x1);
                u16 l0 = bf16rn(x0 - bf16tof(h0)), l1 = bf16rn(x1 - bf16tof(h1));
                hw[t] = (unsigned)h0 | ((unsigned)h1 << 16);
                lw[t] = (unsigned)l0 | ((unsigned)l1 << 16);
            }
            size_t j = (size_t)bg * 49 + t128;
            uint4* r4 = (uint4*)(Qp + j * 32);
            r4[0] = make_uint4(hw[0], hw[1], hw[2], hw[3]);
            r4[1] = make_uint4(hw[4], hw[5], hw[6], hw[7]);
            r4[2] = make_uint4(lw[0], lw[1], lw[2], lw[3]);
            r4[3] = make_uint4(lw[4], lw[5], lw[6], lw[7]);
        }
    } else {                                 // ---- E transpose / rel rows ----
        int e = blk - 2560;
        if (e < 32) {
            int m = e;
            const float* eb = E + (size_t)m * 12544;
            u16* po = EhT + (size_t)m * 14336;
            u16* pl = ElT + (size_t)m * 14336;
            for (int pt = 0; pt < 4; ++pt) {
                int pbase = pt * 49;
                for (int t = tid; t < 3136; t += 256) {
                    int p = t >> 6, h = t & 63;
                    smem[p * 65 + h] = eb[(size_t)(pbase + p) * 64 + h];
                }
                __syncthreads();
                for (int t = tid; t < 3136; t += 256) {
                    int h = t / 49, p = t % 49;
                    float v = smem[p * 65 + h];
                    u16 hi = bf16rn(v);
                    po[h * 224 + pbase + p] = hi;
                    pl[h * 224 + pbase + p] = bf16rn(v - bf16tof(hi));
                }
                __syncthreads();
            }
            for (int t = tid; t < 64 * 28; t += 256) {
                int h = t / 28, p = 196 + t % 28;
                po[h * 224 + p] = 0; pl[h * 224 + p] = 0;
            }
        } else {
            int b = e - 32;
            size_t bK = (size_t)b * 2112;
            size_t bT = (size_t)b * 33792;
#pragma unroll
            for (int k = 0; k < 4; ++k) {
                int idx = tid + k * 256;
                int row = idx >> 4, ee = idx & 15;
                int i = 2048 + row;
                float v = (row < 49) ? rel[ee * 49 + row] : 0.f;
                u16 h = bf16rn(v);
                u16 l = bf16rn(v - bf16tof(h));
                Kh[(bK + i) * 16 + ee] = h;
                Kl[(bK + i) * 16 + ee] = l;
                KhT[bT + (size_t)ee * 2112 + i] = h;
                KlT[bT + (size_t)ee * 2112 + i] = l;
            }
        }
    }
}

// ---------------------------------------------------------------------------
// MFMA key projection; A read directly as bf16 hi/lo (cph/cpl) — no conversion.
__global__ __launch_bounds__(256) void k_kproj2(const u16* __restrict__ cph,
                                                const u16* __restrict__ cpl,
                                                const u16* __restrict__ EhT,
                                                const u16* __restrict__ ElT,
                                                u16* __restrict__ Kh,
                                                u16* __restrict__ Kl,
                                                u16* __restrict__ KhT,
                                                u16* __restrict__ KlT) {
    int blk = blockIdx.x;           // b*32 + m
    int b = blk >> 5, m = blk & 31;
    int wave = threadIdx.x >> 6, lane = threadIdx.x & 63;
    int ht = wave;
    int n = lane & 15, quad = lane >> 4;

    const u16* ahrow = cph + ((size_t)b * 512 + (size_t)n * 32 + m) * 224;
    const u16* alrow = cpl + ((size_t)b * 512 + (size_t)n * 32 + m) * 224;
    const u16* bhrow = EhT + ((size_t)m * 64 + ht * 16 + n) * 224;
    const u16* blrow = ElT + ((size_t)m * 64 + ht * 16 + n) * 224;

    floatx4 c = {0.f, 0.f, 0.f, 0.f};
#pragma unroll
    for (int pc = 0; pc < 7; ++pc) {
        int p0 = pc * 32 + quad * 8;
        short8 ah = ld8(ahrow + p0);
        short8 al = ld8(alrow + p0);
        short8 bh = ld8(bhrow + p0);
        short8 bl = ld8(blrow + p0);
        c = MFMA16(ah, bh, c);
        c = MFMA16(ah, bl, c);
        c = MFMA16(al, bh, c);
    }
    int i = m * 64 + ht * 16 + n;
    size_t bK = (size_t)b * 2112;
    size_t bT = (size_t)b * 33792;
    u16 h[4], l[4];
#pragma unroll
    for (int r = 0; r < 4; ++r) {
        h[r] = bf16rn(c[r]);
        l[r] = bf16rn(c[r] - bf16tof(h[r]));
    }
    *(uint2*)(Kh + (bK + i) * 16 + quad * 4) =
        make_uint2((unsigned)h[0] | ((unsigned)h[1] << 16), (unsigned)h[2] | ((unsigned)h[3] << 16));
    *(uint2*)(Kl + (bK + i) * 16 + quad * 4) =
        make_uint2((unsigned)l[0] | ((unsigned)l[1] << 16), (unsigned)l[2] | ((unsigned)l[3] << 16));
#pragma unroll
    for (int r = 0; r < 4; ++r) {
        KhT[bT + (size_t)(quad * 4 + r) * 2112 + i] = h[r];
        KlT[bT + (size_t)(quad * 4 + r) * 2112 + i] = l[r];
    }
}

// ---------------------------------------------------------------------------
// Column denominators (log2 domain): dpart[jh][b][i] = sum_j exp2(S')
__global__ __launch_bounds__(256) void k_stats5(const u16* __restrict__ Qp,
                                                const u16* __restrict__ Kh,
                                                const u16* __restrict__ Kl,
                                                float* __restrict__ dpart) {
    int blk = blockIdx.x;                   // b*34 + jh*17 + tb
    int b = blk / 34; int rem = blk % 34; int jh = rem / 17; int tb = rem % 17;
    int wave = threadIdx.x >> 6, lane = threadIdx.x & 63;
    int it2 = tb * 4 + wave;
    if (it2 >= 66) return;
    int ibase = it2 * 32;
    int n = lane & 15, quad = lane >> 4;
    size_t bK = (size_t)b * 2112;
    const u16* kb = Kh + (bK + ibase + n) * 16 + (quad & 1) * 8;
    const u16* lb = Kl + (bK + ibase + n) * 16 + (quad & 1) * 8;
    short8 bh0 = ld8(kb), bh1 = ld8(kb + 256);
    short8 bl0 = ld8(lb), bl1 = ld8(lb + 256);
    const u16* qb = Qp + (size_t)b * 50176 + (size_t)jh * 49 * 512 + n * 32 + quad * 8;
    floatx4 d0 = {0.f,0.f,0.f,0.f}, d1 = {0.f,0.f,0.f,0.f};
    short8 a0 = ld8(qb), a1 = ld8(qb + 512);
    for (int c = 0; c < 49; ++c) {
        short8 a2 = (c + 2 < 49) ? ld8(qb + (size_t)(c + 2) * 512) : a0;
        floatx4 s0 = {0.f,0.f,0.f,0.f}, s1 = {0.f,0.f,0.f,0.f};
        s0 = MFMA16(a0, bh0, s0);
        s0 = MFMA16(a0, bl0, s0);
        s1 = MFMA16(a0, bh1, s1);
        s1 = MFMA16(a0, bl1, s1);
        d0.x += exp2fast(s0.x); d0.y += exp2fast(s0.y);
        d0.z += exp2fast(s0.z); d0.w += exp2fast(s0.w);
        d1.x += exp2fast(s1.x); d1.y += exp2fast(s1.y);
        d1.z += exp2fast(s1.z); d1.w += exp2fast(s1.w);
        a0 = a1; a1 = a2;
    }
    float t0 = d0.x + d0.y + d0.z + d0.w;
    float t1 = d1.x + d1.y + d1.z + d1.w;
    t0 += __shfl_xor(t0, 16); t0 += __shfl_xor(t0, 32);
    t1 += __shfl_xor(t1, 16); t1 += __shfl_xor(t1, 32);
    if (quad == 0) {
        dpart[(size_t)jh * 67584 + bK + ibase + n]      = t0;
        dpart[(size_t)jh * 67584 + bK + ibase + 16 + n] = t1;
    }
}

// ---------------------------------------------------------------------------
// PV: conflict-free padded LDS, pipelined W transpose, inline 1/D, i-split x3.
__global__ __launch_bounds__(256) void k_pv7(const u16* __restrict__ Qp,
                                             const u16* __restrict__ Kh,
                                             const u16* __restrict__ Kl,
                                             const u16* __restrict__ KhT,
                                             const u16* __restrict__ KlT,
                                             const float* __restrict__ dpart,
                                             float* __restrict__ opart) {
    __shared__ __align__(16) u16 sH[2][32][24];       // stride 24: <=2-way
    __shared__ __align__(16) u16 sL[2][32][24];
    __shared__ __align__(16) u16 tH[2][16][40];       // stride 40: <=2-way
    __shared__ __align__(16) u16 tL[2][16][40];
    __shared__ __align__(16) u16 w16[4][2][16][40];
    __shared__ float rll[2][32];

    int blk = blockIdx.x;                  // b*75 + jtb*3 + ih
    int b = blk / 75; int rem = blk % 75; int jtb = rem / 3; int ih = rem % 3;
    int tid = threadIdx.x, wave = tid >> 6, lane = tid & 63;
    int n = lane & 15, quad = lane >> 4, qh = quad & 1;
    int jt = jtb * 4 + wave;
    int jtc = jt < 98 ? jt : 97;
    int i0 = ih * 704;                     // 22 chunks of 32
    size_t bK = (size_t)b * 2112;
    size_t bT = (size_t)b * 33792;
    const float* d0p = dpart + bK;
    const float* d1p = dpart + 67584 + bK;

    short8 aq = ld8(Qp + ((size_t)b * 1568 + (size_t)jtc * 16 + n) * 32 + quad * 8);

    int role = wave, L = lane;
    uint4 sreg; float rv = 0.f;
    auto ldchunk = [&](int c) {
        int i0c = i0 + c * 32;
        if (role == 0)      sreg = *(const uint4*)(Kh  + (bK + i0c + (L >> 1)) * 16 + (L & 1) * 8);
        else if (role == 1) sreg = *(const uint4*)(Kl  + (bK + i0c + (L >> 1)) * 16 + (L & 1) * 8);
        else if (role == 2) sreg = *(const uint4*)(KhT + bT + (size_t)(L >> 2) * 2112 + i0c + (L & 3) * 8);
        else {
            sreg = *(const uint4*)(KlT + bT + (size_t)(L >> 2) * 2112 + i0c + (L & 3) * 8);
            if (L < 32) rv = 1.0f / (d0p[i0c + L] + d1p[i0c + L]);
        }
    };
    auto stchunk = [&](int bf) {
        if (role == 0)      *(uint4*)(&sH[bf][L >> 1][(L & 1) * 8]) = sreg;
        else if (role == 1) *(uint4*)(&sL[bf][L >> 1][(L & 1) * 8]) = sreg;
        else if (role == 2) *(uint4*)(&tH[bf][L >> 2][(L & 3) * 8]) = sreg;
        else {
            *(uint4*)(&tL[bf][L >> 2][(L & 3) * 8]) = sreg;
            if (L < 32) rll[bf][L] = rv;
        }
    };

    floatx4 o = {0.f, 0.f, 0.f, 0.f};
    short8 thp = {}, tlp = {};

    ldchunk(0); stchunk(0); ldchunk(1);
    __syncthreads();
    for (int c = 0; c < 22; ++c) {
        int cb = c & 1;
        short8 th  = ld8(&tH[cb][n][quad * 8]);
        short8 tl  = ld8(&tL[cb][n][quad * 8]);
        short8 sh0 = ld8(&sH[cb][n][qh * 8]);
        short8 sh1 = ld8(&sH[cb][16 + n][qh * 8]);
        short8 sl0 = ld8(&sL[cb][n][qh * 8]);
        short8 sl1 = ld8(&sL[cb][16 + n][qh * 8]);
        float r0 = rll[cb][n], r1 = rll[cb][16 + n];
        short8 aw = {};
        if (c > 0) aw = ld8(&w16[wave][1 - cb][n][quad * 8]);   // W of chunk c-1
        floatx4 s0 = {0.f,0.f,0.f,0.f};
        s0 = MFMA16(aq, sh0, s0);
        s0 = MFMA16(aq, sl0, s0);
        floatx4 s1 = {0.f,0.f,0.f,0.f};
        s1 = MFMA16(aq, sh1, s1);
        s1 = MFMA16(aq, sl1, s1);
        if (c > 0) {                                            // PV for chunk c-1
            o = MFMA16(aw, thp, o);
            o = MFMA16(aw, tlp, o);
        }
#pragma unroll
        for (int r = 0; r < 4; ++r) {
            float w0 = exp2fast(s0[r]) * r0;
            float w1 = exp2fast(s1[r]) * r1;
            w16[wave][cb][quad * 4 + r][n]      = (u16)(__float_as_uint(w0) >> 16);
            w16[wave][cb][quad * 4 + r][16 + n] = (u16)(__float_as_uint(w1) >> 16);
        }
        thp = th; tlp = tl;
        if (c + 1 < 22) stchunk(cb ^ 1);
        if (c + 2 < 22) ldchunk(c + 2);
        __syncthreads();
    }
    {   // drain PV for last chunk (c=21, parity 1)
        short8 aw = ld8(&w16[wave][1][n][quad * 8]);
        o = MFMA16(aw, thp, o);
        o = MFMA16(aw, tlp, o);
    }
    if (jt < 98) {
        float* ob = opart + (size_t)ih * 802816 + ((size_t)b * 1568 + (size_t)jt * 16) * 16;
#pragma unroll
        for (int r = 0; r < 4; ++r) ob[(quad * 4 + r) * 16 + n] = o[r];
    }
}

// ---------------------------------------------------------------------------
// Final conv 7x7 (sums 3 opart parts) + LayerNorm, transposed cvout layout.
__global__ __launch_bounds__(128) void k_conv7ln(const float* __restrict__ op0,
                                                 const float* __restrict__ op1,
                                                 const float* __restrict__ op2,
                                                 const float* __restrict__ w,
                                                 const float* __restrict__ gamma,
                                                 const float* __restrict__ beta,
                                                 float* __restrict__ out) {
    int bg = blockIdx.x;           // b*32+g
    int tid = threadIdx.x;
    __shared__ float patch[16 * 144];
    __shared__ float cvout[16][52];
    for (int t = tid; t < 16 * 144; t += 128) patch[t] = 0.f;
    __syncthreads();
    const float* p0 = op0 + (size_t)bg * 784;
    const float* p1 = op1 + (size_t)bg * 784;
    const float* p2 = op2 + (size_t)bg * 784;
    for (int t = tid; t < 784; t += 128) {
        int ic = t / 49, p = t % 49;
        int y = p / 7, x = p % 7;
        patch[ic * 144 + (y + 1) * 16 + (x + 1)] = p0[t] + p1[t] + p2[t];
    }
    __syncthreads();
    int g = bg & 31;
    int oh = tid >> 6, lt = tid & 63;
    const float* wg = w + (size_t)g * 2304 + (size_t)oh * 8 * 144;
    if (lt < 49) {
        int y = lt / 7, x = lt % 7;
        int base = (y + 1) * 16 + (x + 1);
        float acc[8];
#pragma unroll
        for (int oc = 0; oc < 8; ++oc) acc[oc] = 0.f;
        for (int ic = 0; ic < 16; ++ic) {
            const float* pr = patch + ic * 144 + base;
            float win[9];
#pragma unroll
            for (int ky = 0; ky < 3; ++ky)
#pragma unroll
                for (int kx = 0; kx < 3; ++kx)
                    win[ky * 3 + kx] = pr[(ky - 1) * 16 + (kx - 1)];
#pragma unroll
            for (int oc = 0; oc < 8; ++oc)
#pragma unroll
                for (int kk = 0; kk < 9; ++kk)
                    acc[oc] += win[kk] * wg[oc * 144 + ic * 9 + kk];
        }
#pragma unroll
        for (int oc = 0; oc < 8; ++oc) {
            int f = (oh * 8 + oc) * 49 + lt;
            cvout[f & 15][f >> 4] = acc[oc];
        }
    }
    __syncthreads();
    if (tid < 49) {
        float v[16];
        float sum = 0.f;
#pragma unroll
        for (int k = 0; k < 16; ++k) { v[k] = cvout[k][tid]; sum += v[k]; }
        float mu = sum * 0.0625f;
        float var = 0.f;
#pragma unroll
        for (int k = 0; k < 16; ++k) { float d = v[k] - mu; var += d * d; }
        float rstd = rsqrtf(var * 0.0625f + 1e-5f);
        float4 o4[4];
#pragma unroll
        for (int k = 0; k < 16; ++k)
            ((float*)o4)[k] = (v[k] - mu) * rstd * gamma[k] + beta[k];
        float4* po = (float4*)(out + (size_t)bg * 784 + (size_t)tid * 16);
        po[0] = o4[0]; po[1] = o4[1]; po[2] = o4[2]; po[3] = o4[3];
    }
}

// ---------------------------------------------------------------------------
extern "C" void kernel_launch(void* const* d_in, const int* in_sizes, int n_in,
                              void* d_out, int out_size, void* d_ws, size_t ws_size,
                              hipStream_t stream) {
    const float* current_pose = (const float*)d_in[0];
    const float* next_pose    = (const float*)d_in[1];
    const float* current_w    = (const float*)d_in[2];
    const float* next_w       = (const float*)d_in[3];
    const float* E_proj       = (const float*)d_in[4];
    const float* rel          = (const float*)d_in[5];
    const float* ln_gamma     = (const float*)d_in[6];
    const float* ln_beta      = (const float*)d_in[7];
    float* out = (float*)d_out;
    float* ws  = (float*)d_ws;

    // cph/cpl (u16, 32*512*224 each) live at ws start; opart (3x802816 fl)
    // aliases them (written by pv7 strictly after kproj2's last read).
    u16*   cph   = (u16*)ws;                  // u16 [0 .. 3,670,016)
    u16*   cpl   = cph + 3670016;             // u16 [3,670,016 .. 7,340,032)
    float* opart = ws;                        // fl  [0 .. 2,408,448)  (alias)
    float* dpart = ws + 3670016;              // fl  [3,670,016 .. 3,805,184)
    u16*   ub    = (u16*)(ws + 3805184);
    u16* Qp  = ub;                            // 1,605,632
    u16* Kh  = ub + 1605632;                  // 1,081,344
    u16* Kl  = ub + 2686976;
    u16* KhT = ub + 3768320;
    u16* KlT = ub + 4849664;
    u16* EhT = ub + 5931008;                  // 458,752
    u16* ElT = ub + 6389760;                  // ends 6,848,512  (~28.9 MB total)

    k_prep   <<<2624, 256, 0, stream>>>(current_pose, next_pose, E_proj, rel,
                                        current_w, next_w, cph, cpl, Qp,
                                        EhT, ElT, Kh, Kl, KhT, KlT);
    k_kproj2 <<<1024, 256, 0, stream>>>(cph, cpl, EhT, ElT, Kh, Kl, KhT, KlT);
    k_stats5 <<<1088, 256, 0, stream>>>(Qp, Kh, Kl, dpart);
    k_pv7    <<<2400, 256, 0, stream>>>(Qp, Kh, Kl, KhT, KlT, dpart, opart);
    k_conv7ln<<<1024, 128, 0, stream>>>(opart, opart + 802816, opart + 1605632,
                                        next_w, ln_gamma, ln_beta, out);
    (void)in_sizes; (void)n_in; (void)out_size; (void)ws_size;
}

// Round 9
// 236.728 us; speedup vs baseline: 1.0235x; 1.0235x over previous
//
#include <hip/hip_runtime.h>

typedef unsigned short u16;
typedef __attribute__((ext_vector_type(8))) short short8;   // 8 bf16 = 4 VGPRs
typedef __attribute__((ext_vector_type(4))) float floatx4;

#define MFMA16(a, b, c) __builtin_amdgcn_mfma_f32_16x16x32_bf16(a, b, c, 0, 0, 0)

__device__ inline u16 bf16rn(float x) {
    unsigned u = __float_as_uint(x);
    u += 0x7fffu + ((u >> 16) & 1u);
    return (u16)(u >> 16);
}
__device__ inline float bf16tof(u16 h) { return __uint_as_float(((unsigned)h) << 16); }
__device__ inline short8 ld8(const u16* p) { return *(const short8*)p; }
__device__ inline float exp2fast(float x) { return __builtin_amdgcn_exp2f(x); }

// Q scale: 0.25 * log2(e) — S lands in log2 domain, exp(S)=exp2(S')
#define QSC 0.36067376022224085f

// ---------------------------------------------------------------------------
// Fused prep (one dispatch, 3 block ranges):
//  [0,2048):    conv14 (oc-split x2) -> cph/cpl bf16 hi/lo, 224-padded rows
//  [2048,3072): q-conv 7x7 (1 bg, wave-split oc) + Q hi/lo conversion (x QSC)
//  [3072,3136): e<32: E transpose+hi/lo (tiled);  e>=32: rel K rows
// LDS strides chosen conflict-free: conv14 patch 258 (2ic banks), q patch 146.
__global__ __launch_bounds__(256) void k_prep(const float* __restrict__ pose14,
                                              const float* __restrict__ pose7,
                                              const float* __restrict__ E,
                                              const float* __restrict__ rel,
                                              const float* __restrict__ cw,
                                              const float* __restrict__ nw,
                                              u16* __restrict__ cph,
                                              u16* __restrict__ cpl,
                                              u16* __restrict__ Qp,
                                              u16* __restrict__ EhT,
                                              u16* __restrict__ ElT,
                                              u16* __restrict__ Kh,
                                              u16* __restrict__ Kl,
                                              u16* __restrict__ KhT,
                                              u16* __restrict__ KlT) {
    __shared__ __align__(16) float smem[4160];    // 16.6 KB union
    int blk = blockIdx.x, tid = threadIdx.x;

    if (blk < 2048) {                        // ---- conv14 ----
        int oh = blk & 1, bg = blk >> 1;
        float* patch = smem;                 // 16 ic x 258 (16x16 halo, pad 258)
        for (int t = tid; t < 16 * 258; t += 256) patch[t] = 0.f;
        __syncthreads();
        const float* pin = pose14 + (size_t)bg * 3136;
        for (int t = tid; t < 3136; t += 256) {
            int p = t >> 4, ic = t & 15;
            int y = p / 14, x = p % 14;
            patch[ic * 258 + (y + 1) * 16 + (x + 1)] = pin[t];
        }
        __syncthreads();
        int g = bg & 31;
        const float* wg = cw + (size_t)g * 2304 + (size_t)oh * 8 * 144;
        if (tid < 196) {
            int y = tid / 14, x = tid % 14;
            int base = (y + 1) * 16 + (x + 1);
            float acc[8];
#pragma unroll
            for (int oc = 0; oc < 8; ++oc) acc[oc] = 0.f;
            for (int ic = 0; ic < 16; ++ic) {
                const float* pr = patch + ic * 258 + base;
                float win[9];
#pragma unroll
                for (int ky = 0; ky < 3; ++ky)
#pragma unroll
                    for (int kx = 0; kx < 3; ++kx)
                        win[ky * 3 + kx] = pr[(ky - 1) * 16 + (kx - 1)];
#pragma unroll
                for (int oc = 0; oc < 8; ++oc)
#pragma unroll
                    for (int kk = 0; kk < 9; ++kk)
                        acc[oc] += win[kk] * wg[oc * 144 + ic * 9 + kk];
            }
#pragma unroll
            for (int oc = 0; oc < 8; ++oc) {
                size_t row = (size_t)bg * 16 + oh * 8 + oc;
                u16 h = bf16rn(acc[oc]);
                cph[row * 224 + tid] = h;
                cpl[row * 224 + tid] = bf16rn(acc[oc] - bf16tof(h));
            }
        }
    } else if (blk < 3072) {                 // ---- q-conv + Q cvt (1 bg) ----
        int bg = blk - 2048;
        float* patch = smem;                 // 16 ic x 146 (pad 146: 18ic banks)
        float* cvq   = smem + 2336;          // [16][52]
        for (int t = tid; t < 16 * 146; t += 256) patch[t] = 0.f;
        __syncthreads();
        const float* pin = pose7 + (size_t)bg * 784;
        for (int t = tid; t < 784; t += 256) {
            int p = t >> 4, ic = t & 15;
            int y = p / 7, x = p % 7;
            patch[ic * 146 + (y + 1) * 16 + (x + 1)] = pin[t];
        }
        __syncthreads();
        int g = bg & 31;
        int wave = tid >> 6, lt = tid & 63;  // wave-uniform oc quarter
        const float* wg = nw + (size_t)g * 2304 + (size_t)wave * 4 * 144;
        if (lt < 49) {
            int y = lt / 7, x = lt % 7;
            int base = (y + 1) * 16 + (x + 1);
            float acc[4];
#pragma unroll
            for (int oc = 0; oc < 4; ++oc) acc[oc] = 0.f;
            for (int ic = 0; ic < 16; ++ic) {
                const float* pr = patch + ic * 146 + base;
                float win[9];
#pragma unroll
                for (int ky = 0; ky < 3; ++ky)
#pragma unroll
                    for (int kx = 0; kx < 3; ++kx)
                        win[ky * 3 + kx] = pr[(ky - 1) * 16 + (kx - 1)];
#pragma unroll
                for (int oc = 0; oc < 4; ++oc)
#pragma unroll
                    for (int kk = 0; kk < 9; ++kk)
                        acc[oc] += win[kk] * wg[oc * 144 + ic * 9 + kk];
            }
#pragma unroll
            for (int oc = 0; oc < 4; ++oc) {
                int f = (wave * 4 + oc) * 49 + lt;
                cvq[(f & 15) * 52 + (f >> 4)] = acc[oc];
            }
        }
        __syncthreads();
        if (tid < 49) {
            float v[16];
#pragma unroll
            for (int k = 0; k < 16; ++k) v[k] = cvq[k * 52 + tid];
            unsigned hw[8], lw[8];
#pragma unroll
            for (int t = 0; t < 8; ++t) {
                float x0 = v[2*t] * QSC, x1 = v[2*t+1] * QSC;
                u16 h0 = bf16rn(x0), h1 = bf16rn(x1);
                u16 l0 = bf16rn(x0 - bf16tof(h0)), l1 = bf16rn(x1 - bf16tof(h1));
                hw[t] = (unsigned)h0 | ((unsigned)h1 << 16);
                lw[t] = (unsigned)l0 | ((unsigned)l1 << 16);
            }
            size_t j = (size_t)bg * 49 + tid;
            uint4* r4 = (uint4*)(Qp + j * 32);
            r4[0] = make_uint4(hw[0], hw[1], hw[2], hw[3]);
            r4[1] = make_uint4(hw[4], hw[5], hw[6], hw[7]);
            r4[2] = make_uint4(lw[0], lw[1], lw[2], lw[3]);
            r4[3] = make_uint4(lw[4], lw[5], lw[6], lw[7]);
        }
    } else {                                 // ---- E transpose / rel rows ----
        int e = blk - 3072;
        if (e < 32) {
            int m = e;
            const float* eb = E + (size_t)m * 12544;
            u16* po = EhT + (size_t)m * 14336;
            u16* pl = ElT + (size_t)m * 14336;
            for (int pt = 0; pt < 4; ++pt) {
                int pbase = pt * 49;
                for (int t = tid; t < 3136; t += 256) {
                    int p = t >> 6, h = t & 63;
                    smem[p * 65 + h] = eb[(size_t)(pbase + p) * 64 + h];
                }
                __syncthreads();
                for (int t = tid; t < 3136; t += 256) {
                    int h = t / 49, p = t % 49;
                    float v = smem[p * 65 + h];
                    u16 hi = bf16rn(v);
                    po[h * 224 + pbase + p] = hi;
                    pl[h * 224 + pbase + p] = bf16rn(v - bf16tof(hi));
                }
                __syncthreads();
            }
            for (int t = tid; t < 64 * 28; t += 256) {
                int h = t / 28, p = 196 + t % 28;
                po[h * 224 + p] = 0; pl[h * 224 + p] = 0;
            }
        } else {
            int b = e - 32;
            size_t bK = (size_t)b * 2112;
            size_t bT = (size_t)b * 33792;
#pragma unroll
            for (int k = 0; k < 4; ++k) {
                int idx = tid + k * 256;
                int row = idx >> 4, ee = idx & 15;
                int i = 2048 + row;
                float v = (row < 49) ? rel[ee * 49 + row] : 0.f;
                u16 h = bf16rn(v);
                u16 l = bf16rn(v - bf16tof(h));
                Kh[(bK + i) * 16 + ee] = h;
                Kl[(bK + i) * 16 + ee] = l;
                KhT[bT + (size_t)ee * 2112 + i] = h;
                KlT[bT + (size_t)ee * 2112 + i] = l;
            }
        }
    }
}

// ---------------------------------------------------------------------------
// MFMA key projection; A read directly as bf16 hi/lo (cph/cpl) — no conversion.
__global__ __launch_bounds__(256) void k_kproj2(const u16* __restrict__ cph,
                                                const u16* __restrict__ cpl,
                                                const u16* __restrict__ EhT,
                                                const u16* __restrict__ ElT,
                                                u16* __restrict__ Kh,
                                                u16* __restrict__ Kl,
                                                u16* __restrict__ KhT,
                                                u16* __restrict__ KlT) {
    int blk = blockIdx.x;           // b*32 + m
    int b = blk >> 5, m = blk & 31;
    int wave = threadIdx.x >> 6, lane = threadIdx.x & 63;
    int ht = wave;
    int n = lane & 15, quad = lane >> 4;

    const u16* ahrow = cph + ((size_t)b * 512 + (size_t)n * 32 + m) * 224;
    const u16* alrow = cpl + ((size_t)b * 512 + (size_t)n * 32 + m) * 224;
    const u16* bhrow = EhT + ((size_t)m * 64 + ht * 16 + n) * 224;
    const u16* blrow = ElT + ((size_t)m * 64 + ht * 16 + n) * 224;

    floatx4 c = {0.f, 0.f, 0.f, 0.f};
#pragma unroll
    for (int pc = 0; pc < 7; ++pc) {
        int p0 = pc * 32 + quad * 8;
        short8 ah = ld8(ahrow + p0);
        short8 al = ld8(alrow + p0);
        short8 bh = ld8(bhrow + p0);
        short8 bl = ld8(blrow + p0);
        c = MFMA16(ah, bh, c);
        c = MFMA16(ah, bl, c);
        c = MFMA16(al, bh, c);
    }
    int i = m * 64 + ht * 16 + n;
    size_t bK = (size_t)b * 2112;
    size_t bT = (size_t)b * 33792;
    u16 h[4], l[4];
#pragma unroll
    for (int r = 0; r < 4; ++r) {
        h[r] = bf16rn(c[r]);
        l[r] = bf16rn(c[r] - bf16tof(h[r]));
    }
    *(uint2*)(Kh + (bK + i) * 16 + quad * 4) =
        make_uint2((unsigned)h[0] | ((unsigned)h[1] << 16), (unsigned)h[2] | ((unsigned)h[3] << 16));
    *(uint2*)(Kl + (bK + i) * 16 + quad * 4) =
        make_uint2((unsigned)l[0] | ((unsigned)l[1] << 16), (unsigned)l[2] | ((unsigned)l[3] << 16));
#pragma unroll
    for (int r = 0; r < 4; ++r) {
        KhT[bT + (size_t)(quad * 4 + r) * 2112 + i] = h[r];
        KlT[bT + (size_t)(quad * 4 + r) * 2112 + i] = l[r];
    }
}

// ---------------------------------------------------------------------------
// Column denominators (log2 domain): dpart[jh][b][i] = sum_j exp2(S')
__global__ __launch_bounds__(256) void k_stats5(const u16* __restrict__ Qp,
                                                const u16* __restrict__ Kh,
                                                const u16* __restrict__ Kl,
                                                float* __restrict__ dpart) {
    int blk = blockIdx.x;                   // b*34 + jh*17 + tb
    int b = blk / 34; int rem = blk % 34; int jh = rem / 17; int tb = rem % 17;
    int wave = threadIdx.x >> 6, lane = threadIdx.x & 63;
    int it2 = tb * 4 + wave;
    if (it2 >= 66) return;
    int ibase = it2 * 32;
    int n = lane & 15, quad = lane >> 4;
    size_t bK = (size_t)b * 2112;
    const u16* kb = Kh + (bK + ibase + n) * 16 + (quad & 1) * 8;
    const u16* lb = Kl + (bK + ibase + n) * 16 + (quad & 1) * 8;
    short8 bh0 = ld8(kb), bh1 = ld8(kb + 256);
    short8 bl0 = ld8(lb), bl1 = ld8(lb + 256);
    const u16* qb = Qp + (size_t)b * 50176 + (size_t)jh * 49 * 512 + n * 32 + quad * 8;
    floatx4 d0 = {0.f,0.f,0.f,0.f}, d1 = {0.f,0.f,0.f,0.f};
    short8 a0 = ld8(qb), a1 = ld8(qb + 512);
    for (int c = 0; c < 49; ++c) {
        short8 a2 = (c + 2 < 49) ? ld8(qb + (size_t)(c + 2) * 512) : a0;
        floatx4 s0 = {0.f,0.f,0.f,0.f}, s1 = {0.f,0.f,0.f,0.f};
        s0 = MFMA16(a0, bh0, s0);
        s0 = MFMA16(a0, bl0, s0);
        s1 = MFMA16(a0, bh1, s1);
        s1 = MFMA16(a0, bl1, s1);
        d0.x += exp2fast(s0.x); d0.y += exp2fast(s0.y);
        d0.z += exp2fast(s0.z); d0.w += exp2fast(s0.w);
        d1.x += exp2fast(s1.x); d1.y += exp2fast(s1.y);
        d1.z += exp2fast(s1.z); d1.w += exp2fast(s1.w);
        a0 = a1; a1 = a2;
    }
    float t0 = d0.x + d0.y + d0.z + d0.w;
    float t1 = d1.x + d1.y + d1.z + d1.w;
    t0 += __shfl_xor(t0, 16); t0 += __shfl_xor(t0, 32);
    t1 += __shfl_xor(t1, 16); t1 += __shfl_xor(t1, 32);
    if (quad == 0) {
        dpart[(size_t)jh * 67584 + bK + ibase + n]      = t0;
        dpart[(size_t)jh * 67584 + bK + ibase + 16 + n] = t1;
    }
}

// ---------------------------------------------------------------------------
// PV: conflict-free padded LDS, pipelined W transpose, inline 1/D, i-split x3.
__global__ __launch_bounds__(256) void k_pv7(const u16* __restrict__ Qp,
                                             const u16* __restrict__ Kh,
                                             const u16* __restrict__ Kl,
                                             const u16* __restrict__ KhT,
                                             const u16* __restrict__ KlT,
                                             const float* __restrict__ dpart,
                                             float* __restrict__ opart) {
    __shared__ __align__(16) u16 sH[2][32][24];       // stride 24: <=2-way
    __shared__ __align__(16) u16 sL[2][32][24];
    __shared__ __align__(16) u16 tH[2][16][40];       // stride 40: <=2-way
    __shared__ __align__(16) u16 tL[2][16][40];
    __shared__ __align__(16) u16 w16[4][2][16][40];
    __shared__ float rll[2][32];

    int blk = blockIdx.x;                  // b*75 + jtb*3 + ih
    int b = blk / 75; int rem = blk % 75; int jtb = rem / 3; int ih = rem % 3;
    int tid = threadIdx.x, wave = tid >> 6, lane = tid & 63;
    int n = lane & 15, quad = lane >> 4, qh = quad & 1;
    int jt = jtb * 4 + wave;
    int jtc = jt < 98 ? jt : 97;
    int i0 = ih * 704;                     // 22 chunks of 32
    size_t bK = (size_t)b * 2112;
    size_t bT = (size_t)b * 33792;
    const float* d0p = dpart + bK;
    const float* d1p = dpart + 67584 + bK;

    short8 aq = ld8(Qp + ((size_t)b * 1568 + (size_t)jtc * 16 + n) * 32 + quad * 8);

    int role = wave, L = lane;
    uint4 sreg; float rv = 0.f;
    auto ldchunk = [&](int c) {
        int i0c = i0 + c * 32;
        if (role == 0)      sreg = *(const uint4*)(Kh  + (bK + i0c + (L >> 1)) * 16 + (L & 1) * 8);
        else if (role == 1) sreg = *(const uint4*)(Kl  + (bK + i0c + (L >> 1)) * 16 + (L & 1) * 8);
        else if (role == 2) sreg = *(const uint4*)(KhT + bT + (size_t)(L >> 2) * 2112 + i0c + (L & 3) * 8);
        else {
            sreg = *(const uint4*)(KlT + bT + (size_t)(L >> 2) * 2112 + i0c + (L & 3) * 8);
            if (L < 32) rv = 1.0f / (d0p[i0c + L] + d1p[i0c + L]);
        }
    };
    auto stchunk = [&](int bf) {
        if (role == 0)      *(uint4*)(&sH[bf][L >> 1][(L & 1) * 8]) = sreg;
        else if (role == 1) *(uint4*)(&sL[bf][L >> 1][(L & 1) * 8]) = sreg;
        else if (role == 2) *(uint4*)(&tH[bf][L >> 2][(L & 3) * 8]) = sreg;
        else {
            *(uint4*)(&tL[bf][L >> 2][(L & 3) * 8]) = sreg;
            if (L < 32) rll[bf][L] = rv;
        }
    };

    floatx4 o = {0.f, 0.f, 0.f, 0.f};
    short8 thp = {}, tlp = {};

    ldchunk(0); stchunk(0); ldchunk(1);
    __syncthreads();
    for (int c = 0; c < 22; ++c) {
        int cb = c & 1;
        short8 th  = ld8(&tH[cb][n][quad * 8]);
        short8 tl  = ld8(&tL[cb][n][quad * 8]);
        short8 sh0 = ld8(&sH[cb][n][qh * 8]);
        short8 sh1 = ld8(&sH[cb][16 + n][qh * 8]);
        short8 sl0 = ld8(&sL[cb][n][qh * 8]);
        short8 sl1 = ld8(&sL[cb][16 + n][qh * 8]);
        float r0 = rll[cb][n], r1 = rll[cb][16 + n];
        short8 aw = {};
        if (c > 0) aw = ld8(&w16[wave][1 - cb][n][quad * 8]);   // W of chunk c-1
        floatx4 s0 = {0.f,0.f,0.f,0.f};
        s0 = MFMA16(aq, sh0, s0);
        s0 = MFMA16(aq, sl0, s0);
        floatx4 s1 = {0.f,0.f,0.f,0.f};
        s1 = MFMA16(aq, sh1, s1);
        s1 = MFMA16(aq, sl1, s1);
        if (c > 0) {                                            // PV for chunk c-1
            o = MFMA16(aw, thp, o);
            o = MFMA16(aw, tlp, o);
        }
#pragma unroll
        for (int r = 0; r < 4; ++r) {
            float w0 = exp2fast(s0[r]) * r0;
            float w1 = exp2fast(s1[r]) * r1;
            w16[wave][cb][quad * 4 + r][n]      = (u16)(__float_as_uint(w0) >> 16);
            w16[wave][cb][quad * 4 + r][16 + n] = (u16)(__float_as_uint(w1) >> 16);
        }
        thp = th; tlp = tl;
        if (c + 1 < 22) stchunk(cb ^ 1);
        if (c + 2 < 22) ldchunk(c + 2);
        __syncthreads();
    }
    {   // drain PV for last chunk (c=21, parity 1)
        short8 aw = ld8(&w16[wave][1][n][quad * 8]);
        o = MFMA16(aw, thp, o);
        o = MFMA16(aw, tlp, o);
    }
    if (jt < 98) {
        float* ob = opart + (size_t)ih * 802816 + ((size_t)b * 1568 + (size_t)jt * 16) * 16;
#pragma unroll
        for (int r = 0; r < 4; ++r) ob[(quad * 4 + r) * 16 + n] = o[r];
    }
}

// ---------------------------------------------------------------------------
// Final conv 7x7 (sums 3 opart parts) + LayerNorm, transposed cvout layout.
__global__ __launch_bounds__(128) void k_conv7ln(const float* __restrict__ op0,
                                                 const float* __restrict__ op1,
                                                 const float* __restrict__ op2,
                                                 const float* __restrict__ w,
                                                 const float* __restrict__ gamma,
                                                 const float* __restrict__ beta,
                                                 float* __restrict__ out) {
    int bg = blockIdx.x;           // b*32+g
    int tid = threadIdx.x;
    __shared__ float patch[16 * 146];
    __shared__ float cvout[16][52];
    for (int t = tid; t < 16 * 146; t += 128) patch[t] = 0.f;
    __syncthreads();
    const float* p0 = op0 + (size_t)bg * 784;
    const float* p1 = op1 + (size_t)bg * 784;
    const float* p2 = op2 + (size_t)bg * 784;
    for (int t = tid; t < 784; t += 128) {
        int ic = t / 49, p = t % 49;
        int y = p / 7, x = p % 7;
        patch[ic * 146 + (y + 1) * 16 + (x + 1)] = p0[t] + p1[t] + p2[t];
    }
    __syncthreads();
    int g = bg & 31;
    int oh = tid >> 6, lt = tid & 63;
    const float* wg = w + (size_t)g * 2304 + (size_t)oh * 8 * 144;
    if (lt < 49) {
        int y = lt / 7, x = lt % 7;
        int base = (y + 1) * 16 + (x + 1);
        float acc[8];
#pragma unroll
        for (int oc = 0; oc < 8; ++oc) acc[oc] = 0.f;
        for (int ic = 0; ic < 16; ++ic) {
            const float* pr = patch + ic * 146 + base;
            float win[9];
#pragma unroll
            for (int ky = 0; ky < 3; ++ky)
#pragma unroll
                for (int kx = 0; kx < 3; ++kx)
                    win[ky * 3 + kx] = pr[(ky - 1) * 16 + (kx - 1)];
#pragma unroll
            for (int oc = 0; oc < 8; ++oc)
#pragma unroll
                for (int kk = 0; kk < 9; ++kk)
                    acc[oc] += win[kk] * wg[oc * 144 + ic * 9 + kk];
        }
#pragma unroll
        for (int oc = 0; oc < 8; ++oc) {
            int f = (oh * 8 + oc) * 49 + lt;
            cvout[f & 15][f >> 4] = acc[oc];
        }
    }
    __syncthreads();
    if (tid < 49) {
        float v[16];
        float sum = 0.f;
#pragma unroll
        for (int k = 0; k < 16; ++k) { v[k] = cvout[k][tid]; sum += v[k]; }
        float mu = sum * 0.0625f;
        float var = 0.f;
#pragma unroll
        for (int k = 0; k < 16; ++k) { float d = v[k] - mu; var += d * d; }
        float rstd = rsqrtf(var * 0.0625f + 1e-5f);
        float4 o4[4];
#pragma unroll
        for (int k = 0; k < 16; ++k)
            ((float*)o4)[k] = (v[k] - mu) * rstd * gamma[k] + beta[k];
        float4* po = (float4*)(out + (size_t)bg * 784 + (size_t)tid * 16);
        po[0] = o4[0]; po[1] = o4[1]; po[2] = o4[2]; po[3] = o4[3];
    }
}

// ---------------------------------------------------------------------------
extern "C" void kernel_launch(void* const* d_in, const int* in_sizes, int n_in,
                              void* d_out, int out_size, void* d_ws, size_t ws_size,
                              hipStream_t stream) {
    const float* current_pose = (const float*)d_in[0];
    const float* next_pose    = (const float*)d_in[1];
    const float* current_w    = (const float*)d_in[2];
    const float* next_w       = (const float*)d_in[3];
    const float* E_proj       = (const float*)d_in[4];
    const float* rel          = (const float*)d_in[5];
    const float* ln_gamma     = (const float*)d_in[6];
    const float* ln_beta      = (const float*)d_in[7];
    float* out = (float*)d_out;
    float* ws  = (float*)d_ws;

    // cph/cpl (u16, 32*512*224 each) live at ws start; opart (3x802816 fl)
    // aliases them (written by pv7 strictly after kproj2's last read).
    u16*   cph   = (u16*)ws;                  // u16 [0 .. 3,670,016)
    u16*   cpl   = cph + 3670016;             // u16 [3,670,016 .. 7,340,032)
    float* opart = ws;                        // fl  [0 .. 2,408,448)  (alias)
    float* dpart = ws + 3670016;              // fl  [3,670,016 .. 3,805,184)
    u16*   ub    = (u16*)(ws + 3805184);
    u16* Qp  = ub;                            // 1,605,632
    u16* Kh  = ub + 1605632;                  // 1,081,344
    u16* Kl  = ub + 2686976;
    u16* KhT = ub + 3768320;
    u16* KlT = ub + 4849664;
    u16* EhT = ub + 5931008;                  // 458,752
    u16* ElT = ub + 6389760;                  // ends 6,848,512  (~28.9 MB total)

    k_prep   <<<3136, 256, 0, stream>>>(current_pose, next_pose, E_proj, rel,
                                        current_w, next_w, cph, cpl, Qp,
                                        EhT, ElT, Kh, Kl, KhT, KlT);
    k_kproj2 <<<1024, 256, 0, stream>>>(cph, cpl, EhT, ElT, Kh, Kl, KhT, KlT);
    k_stats5 <<<1088, 256, 0, stream>>>(Qp, Kh, Kl, dpart);
    k_pv7    <<<2400, 256, 0, stream>>>(Qp, Kh, Kl, KhT, KlT, dpart, opart);
    k_conv7ln<<<1024, 128, 0, stream>>>(opart, opart + 802816, opart + 1605632,
                                        next_w, ln_gamma, ln_beta, out);
    (void)in_sizes; (void)n_in; (void)out_size; (void)ws_size;
}